// Round 7
// baseline (362.610 us; speedup 1.0000x reference)
//
#include <hip/hip_runtime.h>

// Problem: B=16, T=2048, D=512, H=512, K=2
// M = B*T = 32768 rows, GEMM K-dim = D*K = 1024, N = 3H = 1536.
//
// ws layout (bytes):
//   Abf [32768][1024] bf16 @ 0          (67,108,864)   -- dead after GEMM; scan
//                                                         scratch (P/C/I, 6MB) overlays it
//   Bbf [1536][1024]  bf16 @ 67108864   ( 3,145,728)
//   GT  [1536][32768] bf16 @ 70254592   (100,663,296)  pre-activation, TRANSPOSED
// total 170,917,888 B

#define MTOT 32768
#define NTOT 1536
#define KTOT 1024
#define DCH  512
#define TLEN 2048
#define NB   16

// scan decomposition: chunks of LC2 steps, two-level (aggregate / combine / apply)
#define LC2    32                 // t per chunk
#define NCH    64                 // TLEN / LC2
#define CHAINS 8192               // NB * DCH chains

typedef __bf16 bf16x8 __attribute__((ext_vector_type(8)));
typedef float  f32x4  __attribute__((ext_vector_type(4)));

__device__ __forceinline__ unsigned short f2bf(float x) {
    unsigned u = __float_as_uint(x);
    u += 0x7FFFu + ((u >> 16) & 1u);   // round-to-nearest-even
    return (unsigned short)(u >> 16);
}
__device__ __forceinline__ float sigmoidf_(float x) {
    return 1.f / (1.f + __expf(-x));
}

// ---------------------------------------------------------------------------
// K0: fused input prep (one launch instead of two).
//   blocks [0, 16384):  A bf16 [M][1024], A[m][j] = in[(m-1)*512 + j],
//                       zero when t==0 && j<512
//   blocks [16384, 19456): Bt bf16 [N][1024], Bt[o][kc*512+d] = w[o*1024+d*2+kc]
__global__ __launch_bounds__(256) void make_AB(const float* __restrict__ in,
                                               const float* __restrict__ w,
                                               unsigned short* __restrict__ A,
                                               unsigned short* __restrict__ Bt) {
    const int bx = blockIdx.x;
    if (bx < 16384) {
        size_t i = (size_t)bx * 256 + threadIdx.x;
        size_t e = i * 8;
        size_t m = e >> 10;
        int    j = (int)(e & 1023);
        alignas(16) unsigned short h[8];
        if (((m & (TLEN - 1)) == 0) && (j < DCH)) {
#pragma unroll
            for (int r = 0; r < 8; ++r) h[r] = 0;
        } else {
            const float* src = in + ((long long)m - 1) * DCH + j;
            float4 a = *(const float4*)src;
            float4 b = *(const float4*)(src + 4);
            h[0] = f2bf(a.x); h[1] = f2bf(a.y); h[2] = f2bf(a.z); h[3] = f2bf(a.w);
            h[4] = f2bf(b.x); h[5] = f2bf(b.y); h[6] = f2bf(b.z); h[7] = f2bf(b.w);
        }
        *(int4*)(A + e) = *(const int4*)h;
    } else {
        int i = (bx - 16384) * 256 + threadIdx.x;   // 1536*512 = 786432
        int o = i >> 9, d = i & 511;
        float w0 = w[(size_t)(o * 512 + d) * 2];
        float w1 = w[(size_t)(o * 512 + d) * 2 + 1];
        Bt[(size_t)o * 1024 + d]       = f2bf(w0);
        Bt[(size_t)o * 1024 + 512 + d] = f2bf(w1);
    }
}

// ---------------------------------------------------------------------------
// K2: GEMM, output TRANSPOSED: GT[n][m] = sum_k A[m][k]*Bt[n][k] + bias[n] (bf16)
//
// 8-phase schedule, 256x256 tile, BK=64, 512 thr = 8 waves (2M x 4N).
// LDS = 2 buf x 2 k-half x (A 256x32 16KB + B 256x32 16KB) = 128 KiB.
//
// R6 lesson (MfmaUtil 37%, 5750 cyc/K-tile vs 2480 MFMA floor): TWO barriers
// per phase lockstep the 8 waves into alternating {LDS burst | MFMA burst}.
// R7: ONE barrier per phase, with the counted vmcnt moved BEFORE it.
// Phase = [reads | stage | vmcnt(N) | s_barrier | MFMA(setprio)].
// Correctness (hand-proven, simulated FIFO incl. prologue/tail):
//  (a) stage(p) overwrites a region last read at p-2; any wave at B1(p-1)
//      already passed MFMA(p-2), whose lgkmcnt(0) drained those reads.
//  (b) reads(p) need the region staged at p-5 landed; uniform VMW(8)
//      pre-barrier (1 stage issued/phase, 2 loads/stage) keeps exactly 4
//      stages in flight and drains the stage from 4 phases ago -> every
//      region is certified by a barrier >=1 phase before its first read.
// Waves now slip within a phase window: a wave finishing MFMA(p) early
// issues reads/stage(p+1) while others still MFMA -> LDS || MFMA overlap.
//
// Stage schedule (1 half-tile/phase): ph0 A-k1(t+1), ph1 B-k1(t+1),
// ph2 A-k0(t+2), ph3 B-k0(t+2), ph4 A-k1(t+2), ph5 B-k1(t+2),
// ph6 A-k0(t+3), ph7 B-k0(t+3).
// (R4 lesson: NO __launch_bounds__ min-waves -- it capped VGPR, spilled acc.)
//
// Bank swizzle: quad' = q ^ ((row>>1)&3), folded into the GLOBAL source addr
// (LDS linear for global_load_lds); 0 conflicts measured R3/R6.
// XCD swizzle: grid 768 = 8*96 bijective (FETCH 274 -> 74 MB measured).
__global__ __launch_bounds__(512) void gemm_gates(const unsigned short* __restrict__ A,
                                                  const unsigned short* __restrict__ B,
                                                  const float* __restrict__ bias,
                                                  unsigned short* __restrict__ GT) {
    __shared__ int4 lds4[8192];   // region(d,kh) int4 base = d*4096 + kh*2048; B at +1024

    const int tid = threadIdx.x;
    const int bx0 = blockIdx.x;
    const int bx  = (bx0 & 7) * 96 + (bx0 >> 3);
    const int mT  = bx / 6, nT = bx % 6;
    const int m0  = mT * 256, n0 = nT * 256;

    // staging: thread covers (row = tid>>2 [+128 for 2nd load], quad = tid&3)
    const int sq = (tid & 3) ^ ((tid >> 3) & 3);   // swizzled source quad
    const unsigned short* ga = A + (size_t)(m0 + (tid >> 2)) * 1024 + sq * 8;
    const unsigned short* gb = B + (size_t)(n0 + (tid >> 2)) * 1024 + sq * 8;
    char* ldsc = (char*)lds4;

    const int lane = tid & 63;
    const int wv   = tid >> 6;
    const int wm   = wv >> 2, wn = wv & 3;     // 2 x 4 wave grid
    const int lr   = lane & 15, lq = lane >> 4;

    // frag offsets (int4 units, region-relative)
    int aoff[2][4], boff[4];
#pragma unroll
    for (int ih = 0; ih < 2; ++ih)
#pragma unroll
        for (int i = 0; i < 4; ++i) {
            int r = wm * 128 + ih * 64 + i * 16 + lr;
            aoff[ih][i] = r * 4 + (lq ^ ((r >> 1) & 3));
        }
#pragma unroll
    for (int j = 0; j < 4; ++j) {
        int c = wn * 64 + j * 16 + lr;
        boff[j] = 1024 + c * 4 + (lq ^ ((c >> 1) & 3));
    }

    f32x4 acc[8][4] = {};
    bf16x8 bfr[4];

#define GLL(SRC, DOFF) __builtin_amdgcn_global_load_lds( \
        (__attribute__((address_space(1))) void*)(void*)(SRC), \
        (__attribute__((address_space(3))) void*)(ldsc + (DOFF)), 16, 0, 0)

    // stage one 16KB k-half of K-tile S (2 loads/thread, LDS dest linear)
#define STG_A(S, KH) { const size_t go_ = (size_t)(S) * 64 + (size_t)(KH) * 32; \
        const int db_ = ((((S) & 1) * 4096 + (KH) * 2048) * 16) + tid * 16; \
        GLL(ga + go_, db_); GLL(ga + 131072 + go_, db_ + 8192); }
#define STG_B(S, KH) { const size_t go_ = (size_t)(S) * 64 + (size_t)(KH) * 32; \
        const int db_ = ((((S) & 1) * 4096 + (KH) * 2048) * 16) + 16384 + tid * 16; \
        GLL(gb + go_, db_); GLL(gb + 131072 + go_, db_ + 8192); }

#define VMW(N) asm volatile("s_waitcnt vmcnt(" #N ")" ::: "memory")

    // ONE barrier per phase; vmcnt BEFORE the barrier so the barrier publishes
    // the drain to all waves.  No trailing barrier -> waves slip.
#define PHASE(D, KH, IH, RDB, STG, VM) { \
        const int rg_ = (D) * 4096 + (KH) * 2048; \
        if (RDB) { \
            _Pragma("unroll") \
            for (int j = 0; j < 4; ++j) bfr[j] = __builtin_bit_cast(bf16x8, lds4[rg_ + boff[j]]); \
        } \
        bf16x8 af_[4]; \
        _Pragma("unroll") \
        for (int i = 0; i < 4; ++i) af_[i] = __builtin_bit_cast(bf16x8, lds4[rg_ + aoff[IH][i]]); \
        STG; \
        VM; \
        __builtin_amdgcn_sched_barrier(0); \
        __builtin_amdgcn_s_barrier(); \
        __builtin_amdgcn_sched_barrier(0); \
        __builtin_amdgcn_s_setprio(1); \
        _Pragma("unroll") \
        for (int i = 0; i < 4; ++i) \
            _Pragma("unroll") \
            for (int j = 0; j < 4; ++j) \
                acc[(IH) * 4 + i][j] = __builtin_amdgcn_mfma_f32_16x16x32_bf16( \
                    af_[i], bfr[j], acc[(IH) * 4 + i][j], 0, 0, 0); \
        __builtin_amdgcn_s_setprio(0); \
    }

    // prologue: 6 half-tile stages (FIFO order matters), drain the first 2.
    STG_A(0, 0); STG_B(0, 0); STG_A(0, 1); STG_B(0, 1); STG_A(1, 0); STG_B(1, 0);
    VMW(8);                               // certifies A-k0(0), B-k0(0)
    __builtin_amdgcn_sched_barrier(0);
    __builtin_amdgcn_s_barrier();
    __builtin_amdgcn_sched_barrier(0);

    for (int t = 0; t < 14; t += 2) {     // iters 0..6 (K-tiles 0..13)
        PHASE(0, 0, 0, 1, STG_A(t + 1, 1), VMW(8));
        PHASE(0, 0, 1, 0, STG_B(t + 1, 1), VMW(8));
        PHASE(0, 1, 0, 1, STG_A(t + 2, 0), VMW(8));
        PHASE(0, 1, 1, 0, STG_B(t + 2, 0), VMW(8));
        PHASE(1, 0, 0, 1, STG_A(t + 2, 1), VMW(8));
        PHASE(1, 0, 1, 0, STG_B(t + 2, 1), VMW(8));
        PHASE(1, 1, 0, 1, STG_A(t + 3, 0), VMW(8));
        PHASE(1, 1, 1, 0, STG_B(t + 3, 0), VMW(8));
    }
    // tail iter (K-tiles 14,15): only t15's k1 still needs staging.
    // Drain schedule simulated: 8,8,4,4,0,0,-,- certifies every tail read.
    PHASE(0, 0, 0, 1, STG_A(15, 1), VMW(8));
    PHASE(0, 0, 1, 0, STG_B(15, 1), VMW(8));
    PHASE(0, 1, 0, 1, ((void)0),    VMW(4));
    PHASE(0, 1, 1, 0, ((void)0),    VMW(4));
    PHASE(1, 0, 0, 1, ((void)0),    VMW(0));
    PHASE(1, 0, 1, 0, ((void)0),    VMW(0));
    PHASE(1, 1, 0, 1, ((void)0),    ((void)0));
    PHASE(1, 1, 1, 0, ((void)0),    ((void)0));

#undef PHASE
#undef VMW
#undef STG_A
#undef STG_B
#undef GLL

    // epilogue: C/D layout col(n)=lane&15, row(m)=(lane>>4)*4+r.
    // acc[I][j] rows = wm*128 + I*16.  4 consecutive m -> int2 store.
#pragma unroll
    for (int j = 0; j < 4; ++j) {
        int gn = n0 + wn * 64 + j * 16 + lr;
        float bj = bias[gn];
#pragma unroll
        for (int i = 0; i < 8; ++i) {
            int gm = m0 + wm * 128 + i * 16 + lq * 4;
            alignas(8) unsigned short pk[4];
#pragma unroll
            for (int r = 0; r < 4; ++r) pk[r] = f2bf(acc[i][j][r] + bj);
            *(int2*)(GT + (size_t)gn * MTOT + gm) = *(const int2*)pk;
        }
    }
}

// ---------------------------------------------------------------------------
// Scan, 3-kernel two-level decomposition.
// R1 lesson: lanes stride 64KB apart, so a lane's chunk must NOT be consumed
// 16B-per-loop-iteration (line evicted before reuse -> 4x sector overfetch).
// Fix: issue ALL chunk loads back-to-back into registers, then recurrence.
// R4: LC2 32 -> 2048 blocks for part1/3 = 32 waves/CU (measured -29 us).
//
// S1: per-chunk aggregates (P = prod f, C = fo-pool with c0=0).
__global__ __launch_bounds__(256) void scan_part1(const unsigned short* __restrict__ GT,
                                                  float* __restrict__ Pws,
                                                  float* __restrict__ Cws) {
    const int tid   = threadIdx.x;
    const int h_loc = tid & 31;
    const int sc    = tid >> 5;           // 0..7
    const int bid   = blockIdx.x;
    const int tg    = bid & 7;
    const int hg    = (bid >> 3) & 15;
    const int b     = bid >> 7;
    const int h     = hg * 32 + h_loc;
    const int cg    = tg * 8 + sc;        // chunk index 0..63

    const size_t mbase = (size_t)b * TLEN + (size_t)cg * LC2;
    const unsigned short* gz = GT + (size_t)h * MTOT + mbase;
    const unsigned short* gf = GT + (size_t)(DCH + h) * MTOT + mbase;

    bf16x8 zv[4], fv[4];
#pragma unroll
    for (int q = 0; q < 4; ++q) zv[q] = *(const bf16x8*)(gz + q * 8);
#pragma unroll
    for (int q = 0; q < 4; ++q) fv[q] = *(const bf16x8*)(gf + q * 8);

    float P = 1.f, c = 0.f;
#pragma unroll
    for (int q = 0; q < 4; ++q)
#pragma unroll
        for (int r = 0; r < 8; ++r) {
            float f = sigmoidf_((float)fv[q][r]);
            float z = 2.f * sigmoidf_(2.f * (float)zv[q][r]) - 1.f;   // tanh
            c = f * c + (1.f - f) * z;
            P *= f;
        }
    const int ch = b * DCH + h;           // chain index, [cg][ch] layout -> coalesced
    Pws[(size_t)cg * CHAINS + ch] = P;
    Cws[(size_t)cg * CHAINS + ch] = c;
}

// S2: exclusive scan over the 64 chunk aggregates of each chain.
__global__ __launch_bounds__(256) void scan_part2(const float* __restrict__ Pws,
                                                  const float* __restrict__ Cws,
                                                  float* __restrict__ Iws) {
    const int ch = blockIdx.x * 256 + threadIdx.x;   // 0..8191
    float cc = 0.f;
    for (int blk = 0; blk < NCH / 16; ++blk) {
        float Pv[16], Cv[16];
#pragma unroll
        for (int i = 0; i < 16; ++i) Pv[i] = Pws[(size_t)(blk * 16 + i) * CHAINS + ch];
#pragma unroll
        for (int i = 0; i < 16; ++i) Cv[i] = Cws[(size_t)(blk * 16 + i) * CHAINS + ch];
#pragma unroll
        for (int i = 0; i < 16; ++i) {
            Iws[(size_t)(blk * 16 + i) * CHAINS + ch] = cc;
            cc = Pv[i] * cc + Cv[i];
        }
    }
}

// S3: apply pass — recompute each chunk with the correct carry-in, write outputs.
__global__ __launch_bounds__(256) void scan_part3(const unsigned short* __restrict__ GT,
                                                  const float* __restrict__ Iws,
                                                  float* __restrict__ out) {
    const int tid   = threadIdx.x;
    const int h_loc = tid & 31;
    const int sc    = tid >> 5;
    const int bid   = blockIdx.x;
    const int tg    = bid & 7;
    const int hg    = (bid >> 3) & 15;
    const int b     = bid >> 7;
    const int h     = hg * 32 + h_loc;
    const int cg    = tg * 8 + sc;

    const size_t mbase = (size_t)b * TLEN + (size_t)cg * LC2;
    const unsigned short* gz = GT + (size_t)h * MTOT + mbase;
    const unsigned short* gf = GT + (size_t)(DCH + h) * MTOT + mbase;
    const unsigned short* go = GT + (size_t)(2 * DCH + h) * MTOT + mbase;

    bf16x8 zv[4], fv[4], ov[4];
#pragma unroll
    for (int q = 0; q < 4; ++q) zv[q] = *(const bf16x8*)(gz + q * 8);
#pragma unroll
    for (int q = 0; q < 4; ++q) fv[q] = *(const bf16x8*)(gf + q * 8);
#pragma unroll
    for (int q = 0; q < 4; ++q) ov[q] = *(const bf16x8*)(go + q * 8);

    const int ch = b * DCH + h;
    float c = Iws[(size_t)cg * CHAINS + ch];

    const size_t BTH = (size_t)NB * TLEN * DCH;
    float* oC  = out + mbase * DCH + h;
    float* oOC = oC + BTH;
#pragma unroll
    for (int q = 0; q < 4; ++q)
#pragma unroll
        for (int r = 0; r < 8; ++r) {
            float f = sigmoidf_((float)fv[q][r]);
            float z = 2.f * sigmoidf_(2.f * (float)zv[q][r]) - 1.f;
            float o = sigmoidf_((float)ov[q][r]);
            c = f * c + (1.f - f) * z;
            __builtin_nontemporal_store(c,     oC  + (size_t)(q * 8 + r) * DCH);
            __builtin_nontemporal_store(o * c, oOC + (size_t)(q * 8 + r) * DCH);
        }
}

// ---------------------------------------------------------------------------
extern "C" void kernel_launch(void* const* d_in, const int* in_sizes, int n_in,
                              void* d_out, int out_size, void* d_ws, size_t ws_size,
                              hipStream_t stream) {
    const float* in   = (const float*)d_in[0];   // [16,2048,512] f32
    const float* w    = (const float*)d_in[1];   // [1536,512,2] f32
    const float* bias = (const float*)d_in[2];   // [1536] f32
    float* out = (float*)d_out;                  // [2][16,2048,512] f32

    unsigned short* Abf = (unsigned short*)d_ws;
    unsigned short* Bbf = Abf + (size_t)MTOT * 1024;
    unsigned short* GT  = Bbf + (size_t)NTOT * 1024;

    // scan scratch overlays Abf (dead after the GEMM): 3 * 2 MB
    float* Pws = (float*)d_ws;
    float* Cws = Pws + (size_t)NCH * CHAINS;
    float* Iws = Cws + (size_t)NCH * CHAINS;

    make_AB<<<dim3(19456), dim3(256), 0, stream>>>(in, w, Abf, Bbf);
    gemm_gates<<<dim3(768), dim3(512), 0, stream>>>(Abf, Bbf, bias, GT);
    scan_part1<<<dim3(2048), dim3(256), 0, stream>>>(GT, Pws, Cws);
    scan_part2<<<dim3(CHAINS / 256), dim3(256), 0, stream>>>(Pws, Cws, Iws);
    scan_part3<<<dim3(2048), dim3(256), 0, stream>>>(GT, Iws, out);
}

// Round 8
// 347.172 us; speedup vs baseline: 1.0445x; 1.0445x over previous
//
#include <hip/hip_runtime.h>

// Problem: B=16, T=2048, D=512, H=512, K=2
// M = B*T = 32768 rows, GEMM K-dim = D*K = 1024, N = 3H = 1536.
//
// ws layout (bytes):
//   Abf [32768][1024] bf16 @ 0          (67,108,864)   -- dead after GEMM; scan
//                                                         scratch (P/C, 4MB) overlays it
//   Bbf [1536][1024]  bf16 @ 67108864   ( 3,145,728)
//   GT  [1536][32768] bf16 @ 70254592   (100,663,296)  pre-activation, TRANSPOSED
// total 170,917,888 B
//
// R7 budget audit: every round's total ≈ Σ(kernel dur) + N_launches × ~27 µs
// (fits R0..R7).  Launch count is a first-order cost -> R8 merges the
// inter-chunk scan (old part2) into the apply pass: 5 launches -> 4.

#define MTOT 32768
#define NTOT 1536
#define KTOT 1024
#define DCH  512
#define TLEN 2048
#define NB   16

// scan decomposition: chunks of LC2 steps, two-level (aggregate / apply-with-lookback)
#define LC2    32                 // t per chunk
#define NCH    64                 // TLEN / LC2
#define CHAINS 8192               // NB * DCH chains

typedef __bf16 bf16x8 __attribute__((ext_vector_type(8)));
typedef float  f32x4  __attribute__((ext_vector_type(4)));

__device__ __forceinline__ unsigned short f2bf(float x) {
    unsigned u = __float_as_uint(x);
    u += 0x7FFFu + ((u >> 16) & 1u);   // round-to-nearest-even
    return (unsigned short)(u >> 16);
}
__device__ __forceinline__ float sigmoidf_(float x) {
    return 1.f / (1.f + __expf(-x));
}

// ---------------------------------------------------------------------------
// K0: fused input prep (one launch instead of two).
//   blocks [0, 16384):  A bf16 [M][1024], A[m][j] = in[(m-1)*512 + j],
//                       zero when t==0 && j<512
//   blocks [16384, 19456): Bt bf16 [N][1024], Bt[o][kc*512+d] = w[o*1024+d*2+kc]
__global__ __launch_bounds__(256) void make_AB(const float* __restrict__ in,
                                               const float* __restrict__ w,
                                               unsigned short* __restrict__ A,
                                               unsigned short* __restrict__ Bt) {
    const int bx = blockIdx.x;
    if (bx < 16384) {
        size_t i = (size_t)bx * 256 + threadIdx.x;
        size_t e = i * 8;
        size_t m = e >> 10;
        int    j = (int)(e & 1023);
        alignas(16) unsigned short h[8];
        if (((m & (TLEN - 1)) == 0) && (j < DCH)) {
#pragma unroll
            for (int r = 0; r < 8; ++r) h[r] = 0;
        } else {
            const float* src = in + ((long long)m - 1) * DCH + j;
            float4 a = *(const float4*)src;
            float4 b = *(const float4*)(src + 4);
            h[0] = f2bf(a.x); h[1] = f2bf(a.y); h[2] = f2bf(a.z); h[3] = f2bf(a.w);
            h[4] = f2bf(b.x); h[5] = f2bf(b.y); h[6] = f2bf(b.z); h[7] = f2bf(b.w);
        }
        *(int4*)(A + e) = *(const int4*)h;
    } else {
        int i = (bx - 16384) * 256 + threadIdx.x;   // 1536*512 = 786432
        int o = i >> 9, d = i & 511;
        float w0 = w[(size_t)(o * 512 + d) * 2];
        float w1 = w[(size_t)(o * 512 + d) * 2 + 1];
        Bt[(size_t)o * 1024 + d]       = f2bf(w0);
        Bt[(size_t)o * 1024 + 512 + d] = f2bf(w1);
    }
}

// ---------------------------------------------------------------------------
// K2: GEMM, output TRANSPOSED: GT[n][m] = sum_k A[m][k]*Bt[n][k] + bias[n] (bf16)
//
// 8-phase schedule, 256x256 tile, BK=64, 512 thr = 8 waves (2M x 4N).
// LDS = 2 buf x 2 k-half x (A 256x32 16KB + B 256x32 16KB) = 128 KiB.
// ONE barrier per phase, counted vmcnt moved BEFORE it (R7: 115->106 us,
// MfmaUtil 42%).  Phase = [reads | stage | vmcnt(8) | s_barrier | MFMA].
// Correctness ledger: stage(p) overwrites a region last read at p-2 (drained
// by that wave's lgkmcnt before MFMA(p-2), certified by barrier(p-1));
// uniform VMW(8) pre-barrier keeps exactly 4 stages (8 loads) in flight and
// drains the stage from 4 phases ago before its first read 1 phase later.
// (R4 lesson: NO __launch_bounds__ min-waves -- it capped VGPR, spilled acc.)
//
// Bank swizzle: quad' = q ^ ((row>>1)&3), folded into the GLOBAL source addr
// (LDS linear for global_load_lds); 0 conflicts measured R3/R6.
// XCD swizzle: grid 768 = 8*96 bijective (FETCH 274 -> 74 MB measured).
__global__ __launch_bounds__(512) void gemm_gates(const unsigned short* __restrict__ A,
                                                  const unsigned short* __restrict__ B,
                                                  const float* __restrict__ bias,
                                                  unsigned short* __restrict__ GT) {
    __shared__ int4 lds4[8192];   // region(d,kh) int4 base = d*4096 + kh*2048; B at +1024

    const int tid = threadIdx.x;
    const int bx0 = blockIdx.x;
    const int bx  = (bx0 & 7) * 96 + (bx0 >> 3);
    const int mT  = bx / 6, nT = bx % 6;
    const int m0  = mT * 256, n0 = nT * 256;

    // staging: thread covers (row = tid>>2 [+128 for 2nd load], quad = tid&3)
    const int sq = (tid & 3) ^ ((tid >> 3) & 3);   // swizzled source quad
    const unsigned short* ga = A + (size_t)(m0 + (tid >> 2)) * 1024 + sq * 8;
    const unsigned short* gb = B + (size_t)(n0 + (tid >> 2)) * 1024 + sq * 8;
    char* ldsc = (char*)lds4;

    const int lane = tid & 63;
    const int wv   = tid >> 6;
    const int wm   = wv >> 2, wn = wv & 3;     // 2 x 4 wave grid
    const int lr   = lane & 15, lq = lane >> 4;

    // frag offsets (int4 units, region-relative)
    int aoff[2][4], boff[4];
#pragma unroll
    for (int ih = 0; ih < 2; ++ih)
#pragma unroll
        for (int i = 0; i < 4; ++i) {
            int r = wm * 128 + ih * 64 + i * 16 + lr;
            aoff[ih][i] = r * 4 + (lq ^ ((r >> 1) & 3));
        }
#pragma unroll
    for (int j = 0; j < 4; ++j) {
        int c = wn * 64 + j * 16 + lr;
        boff[j] = 1024 + c * 4 + (lq ^ ((c >> 1) & 3));
    }

    f32x4 acc[8][4] = {};
    bf16x8 bfr[4];

#define GLL(SRC, DOFF) __builtin_amdgcn_global_load_lds( \
        (__attribute__((address_space(1))) void*)(void*)(SRC), \
        (__attribute__((address_space(3))) void*)(ldsc + (DOFF)), 16, 0, 0)

    // stage one 16KB k-half of K-tile S (2 loads/thread, LDS dest linear)
#define STG_A(S, KH) { const size_t go_ = (size_t)(S) * 64 + (size_t)(KH) * 32; \
        const int db_ = ((((S) & 1) * 4096 + (KH) * 2048) * 16) + tid * 16; \
        GLL(ga + go_, db_); GLL(ga + 131072 + go_, db_ + 8192); }
#define STG_B(S, KH) { const size_t go_ = (size_t)(S) * 64 + (size_t)(KH) * 32; \
        const int db_ = ((((S) & 1) * 4096 + (KH) * 2048) * 16) + 16384 + tid * 16; \
        GLL(gb + go_, db_); GLL(gb + 131072 + go_, db_ + 8192); }

#define VMW(N) asm volatile("s_waitcnt vmcnt(" #N ")" ::: "memory")

    // ONE barrier per phase; vmcnt BEFORE the barrier so the barrier publishes
    // the drain to all waves.  No trailing barrier -> waves slip.
#define PHASE(D, KH, IH, RDB, STG, VM) { \
        const int rg_ = (D) * 4096 + (KH) * 2048; \
        if (RDB) { \
            _Pragma("unroll") \
            for (int j = 0; j < 4; ++j) bfr[j] = __builtin_bit_cast(bf16x8, lds4[rg_ + boff[j]]); \
        } \
        bf16x8 af_[4]; \
        _Pragma("unroll") \
        for (int i = 0; i < 4; ++i) af_[i] = __builtin_bit_cast(bf16x8, lds4[rg_ + aoff[IH][i]]); \
        STG; \
        VM; \
        __builtin_amdgcn_sched_barrier(0); \
        __builtin_amdgcn_s_barrier(); \
        __builtin_amdgcn_sched_barrier(0); \
        __builtin_amdgcn_s_setprio(1); \
        _Pragma("unroll") \
        for (int i = 0; i < 4; ++i) \
            _Pragma("unroll") \
            for (int j = 0; j < 4; ++j) \
                acc[(IH) * 4 + i][j] = __builtin_amdgcn_mfma_f32_16x16x32_bf16( \
                    af_[i], bfr[j], acc[(IH) * 4 + i][j], 0, 0, 0); \
        __builtin_amdgcn_s_setprio(0); \
    }

    // prologue: 6 half-tile stages (FIFO order matters), drain the first 2.
    STG_A(0, 0); STG_B(0, 0); STG_A(0, 1); STG_B(0, 1); STG_A(1, 0); STG_B(1, 0);
    VMW(8);                               // certifies A-k0(0), B-k0(0)
    __builtin_amdgcn_sched_barrier(0);
    __builtin_amdgcn_s_barrier();
    __builtin_amdgcn_sched_barrier(0);

    for (int t = 0; t < 14; t += 2) {     // iters 0..6 (K-tiles 0..13)
        PHASE(0, 0, 0, 1, STG_A(t + 1, 1), VMW(8));
        PHASE(0, 0, 1, 0, STG_B(t + 1, 1), VMW(8));
        PHASE(0, 1, 0, 1, STG_A(t + 2, 0), VMW(8));
        PHASE(0, 1, 1, 0, STG_B(t + 2, 0), VMW(8));
        PHASE(1, 0, 0, 1, STG_A(t + 2, 1), VMW(8));
        PHASE(1, 0, 1, 0, STG_B(t + 2, 1), VMW(8));
        PHASE(1, 1, 0, 1, STG_A(t + 3, 0), VMW(8));
        PHASE(1, 1, 1, 0, STG_B(t + 3, 0), VMW(8));
    }
    // tail iter (K-tiles 14,15): only t15's k1 still needs staging.
    // Drain schedule simulated: 8,8,4,4,0,0,-,- certifies every tail read.
    PHASE(0, 0, 0, 1, STG_A(15, 1), VMW(8));
    PHASE(0, 0, 1, 0, STG_B(15, 1), VMW(8));
    PHASE(0, 1, 0, 1, ((void)0),    VMW(4));
    PHASE(0, 1, 1, 0, ((void)0),    VMW(4));
    PHASE(1, 0, 0, 1, ((void)0),    VMW(0));
    PHASE(1, 0, 1, 0, ((void)0),    VMW(0));
    PHASE(1, 1, 0, 1, ((void)0),    ((void)0));
    PHASE(1, 1, 1, 0, ((void)0),    ((void)0));

#undef PHASE
#undef VMW
#undef STG_A
#undef STG_B
#undef GLL

    // epilogue: C/D layout col(n)=lane&15, row(m)=(lane>>4)*4+r.
    // acc[I][j] rows = wm*128 + I*16.  4 consecutive m -> int2 store.
#pragma unroll
    for (int j = 0; j < 4; ++j) {
        int gn = n0 + wn * 64 + j * 16 + lr;
        float bj = bias[gn];
#pragma unroll
        for (int i = 0; i < 8; ++i) {
            int gm = m0 + wm * 128 + i * 16 + lq * 4;
            alignas(8) unsigned short pk[4];
#pragma unroll
            for (int r = 0; r < 4; ++r) pk[r] = f2bf(acc[i][j][r] + bj);
            *(int2*)(GT + (size_t)gn * MTOT + gm) = *(const int2*)pk;
        }
    }
}

// ---------------------------------------------------------------------------
// Scan, 2-kernel decomposition (R8: lookback scan inlined into apply).
// R1 lesson: lanes stride 64KB apart, so a lane's chunk must NOT be consumed
// 16B-per-loop-iteration (line evicted before reuse -> 4x sector overfetch).
// Fix: issue ALL chunk loads back-to-back into registers, then recurrence.
//
// S1: per-chunk aggregates (P = prod f, C = fo-pool with c0=0).
//     Block = 256 thr = 32 h x 8 chunks; grid = 16b*16hg*8tg = 2048 blocks.
__global__ __launch_bounds__(256) void scan_part1(const unsigned short* __restrict__ GT,
                                                  float* __restrict__ Pws,
                                                  float* __restrict__ Cws) {
    const int tid   = threadIdx.x;
    const int h_loc = tid & 31;
    const int sc    = tid >> 5;           // 0..7
    const int bid   = blockIdx.x;
    const int tg    = bid & 7;
    const int hg    = (bid >> 3) & 15;
    const int b     = bid >> 7;
    const int h     = hg * 32 + h_loc;
    const int cg    = tg * 8 + sc;        // chunk index 0..63

    const size_t mbase = (size_t)b * TLEN + (size_t)cg * LC2;
    const unsigned short* gz = GT + (size_t)h * MTOT + mbase;
    const unsigned short* gf = GT + (size_t)(DCH + h) * MTOT + mbase;

    bf16x8 zv[4], fv[4];
#pragma unroll
    for (int q = 0; q < 4; ++q) zv[q] = *(const bf16x8*)(gz + q * 8);
#pragma unroll
    for (int q = 0; q < 4; ++q) fv[q] = *(const bf16x8*)(gf + q * 8);

    float P = 1.f, c = 0.f;
#pragma unroll
    for (int q = 0; q < 4; ++q)
#pragma unroll
        for (int r = 0; r < 8; ++r) {
            float f = sigmoidf_((float)fv[q][r]);
            float z = 2.f * sigmoidf_(2.f * (float)zv[q][r]) - 1.f;   // tanh
            c = f * c + (1.f - f) * z;
            P *= f;
        }
    const int ch = b * DCH + h;           // chain index, [cg][ch] layout -> coalesced
    Pws[(size_t)cg * CHAINS + ch] = P;
    Cws[(size_t)cg * CHAINS + ch] = c;
}

// S2: apply pass with INLINE LOOKBACK.  Each thread recomputes its chain's
// exclusive prefix over chunk aggregates 0..cg-1 directly from Pws/Cws
// (16-wide register bursts, identity-padded: c = 1*c + 0 is exact; arithmetic
// order identical to the old part2 -> bit-identical result).  The aggregate
// arrays are 4 MB (L2-hot); ~268 MB of redundant reads cost ~8 us of L2 BW,
// overlapped with the gate loads issued beforehand.  full = cg>>4 is
// block-uniform (tg per-block), so the burst loop does not diverge.
__global__ __launch_bounds__(256) void scan_apply(const unsigned short* __restrict__ GT,
                                                  const float* __restrict__ Pws,
                                                  const float* __restrict__ Cws,
                                                  float* __restrict__ out) {
    const int tid   = threadIdx.x;
    const int h_loc = tid & 31;
    const int sc    = tid >> 5;
    const int bid   = blockIdx.x;
    const int tg    = bid & 7;
    const int hg    = (bid >> 3) & 15;
    const int b     = bid >> 7;
    const int h     = hg * 32 + h_loc;
    const int cg    = tg * 8 + sc;

    const size_t mbase = (size_t)b * TLEN + (size_t)cg * LC2;
    const unsigned short* gz = GT + (size_t)h * MTOT + mbase;
    const unsigned short* gf = GT + (size_t)(DCH + h) * MTOT + mbase;
    const unsigned short* go = GT + (size_t)(2 * DCH + h) * MTOT + mbase;

    // issue gate loads FIRST; HBM latency hides under the lookback scan
    bf16x8 zv[4], fv[4], ov[4];
#pragma unroll
    for (int q = 0; q < 4; ++q) zv[q] = *(const bf16x8*)(gz + q * 8);
#pragma unroll
    for (int q = 0; q < 4; ++q) fv[q] = *(const bf16x8*)(gf + q * 8);
#pragma unroll
    for (int q = 0; q < 4; ++q) ov[q] = *(const bf16x8*)(go + q * 8);

    // ---- inline lookback: exclusive prefix over chunks 0..cg-1
    const int ch   = b * DCH + h;
    const int full = cg >> 4;             // block-uniform
    const int rem  = cg & 15;
    float c = 0.f;
    for (int blk = 0; blk <= full; ++blk) {
        const int base = blk * 16;
        const int lim  = (blk == full) ? rem : 16;
        float Pv[16], Cv[16];
#pragma unroll
        for (int i = 0; i < 16; ++i) {
            bool a = i < lim;
            Pv[i] = a ? Pws[(size_t)(base + i) * CHAINS + ch] : 1.f;
            Cv[i] = a ? Cws[(size_t)(base + i) * CHAINS + ch] : 0.f;
        }
#pragma unroll
        for (int i = 0; i < 16; ++i) c = Pv[i] * c + Cv[i];
    }

    // ---- apply + store (nontemporal: outputs never re-read)
    const size_t BTH = (size_t)NB * TLEN * DCH;
    float* oC  = out + mbase * DCH + h;
    float* oOC = oC + BTH;
#pragma unroll
    for (int q = 0; q < 4; ++q)
#pragma unroll
        for (int r = 0; r < 8; ++r) {
            float f = sigmoidf_((float)fv[q][r]);
            float z = 2.f * sigmoidf_(2.f * (float)zv[q][r]) - 1.f;
            float o = sigmoidf_((float)ov[q][r]);
            c = f * c + (1.f - f) * z;
            __builtin_nontemporal_store(c,     oC  + (size_t)(q * 8 + r) * DCH);
            __builtin_nontemporal_store(o * c, oOC + (size_t)(q * 8 + r) * DCH);
        }
}

// ---------------------------------------------------------------------------
extern "C" void kernel_launch(void* const* d_in, const int* in_sizes, int n_in,
                              void* d_out, int out_size, void* d_ws, size_t ws_size,
                              hipStream_t stream) {
    const float* in   = (const float*)d_in[0];   // [16,2048,512] f32
    const float* w    = (const float*)d_in[1];   // [1536,512,2] f32
    const float* bias = (const float*)d_in[2];   // [1536] f32
    float* out = (float*)d_out;                  // [2][16,2048,512] f32

    unsigned short* Abf = (unsigned short*)d_ws;
    unsigned short* Bbf = Abf + (size_t)MTOT * 1024;
    unsigned short* GT  = Bbf + (size_t)NTOT * 1024;

    // scan scratch overlays Abf (dead after the GEMM): 2 * 2 MB
    float* Pws = (float*)d_ws;
    float* Cws = Pws + (size_t)NCH * CHAINS;

    make_AB<<<dim3(19456), dim3(256), 0, stream>>>(in, w, Abf, Bbf);
    gemm_gates<<<dim3(768), dim3(512), 0, stream>>>(Abf, Bbf, bias, GT);
    scan_part1<<<dim3(2048), dim3(256), 0, stream>>>(GT, Pws, Cws);
    scan_apply<<<dim3(2048), dim3(256), 0, stream>>>(GT, Pws, Cws, out);
}